// Round 7
// baseline (518.960 us; speedup 1.0000x reference)
//
#include <hip/hip_runtime.h>
#include <math.h>

#define N_PTS  131072
#define DIM    128
#define NBOOK  4
#define KCODES 1024

#define CHUNK   32                   // codes per chunk
#define NCH_ALL 128                  // 4 books x 32 chunks
#define BPTS    128                  // 4 waves x 32 points
#define SLOTS   13                   // 8 ch-bf16 + 4 cl-i8 + 1 csq
#define CHUNK_BYTES (SLOTS * 1024)   // 13312
#define CHUNK_U16   (SLOTS * 512)    // 6656
#define EPS_ACC 3.5e-3f              // margin guard (trunc 5e-4 + 6-sigma err ~3e-3)
#define WL_CAP  131072
#define C17     7.62939453125e-6f    // 2^-17 = 1/(16*8192)

typedef short  bf16x8 __attribute__((ext_vector_type(8)));
typedef float  f32x16 __attribute__((ext_vector_type(16)));
typedef int    i32x4  __attribute__((ext_vector_type(4)));
typedef int    i32x16 __attribute__((ext_vector_type(16)));
typedef unsigned short u16;

// ws: cbf (128*13312 = 1703936 B) | csq fp32[4096] | counter | worklist
#define WS_CSQ_OFF  1703936u
#define WS_CNT_OFF  (WS_CSQ_OFF + 16384u)
#define WS_WL_OFF   (WS_CNT_OFF + 256u)

__device__ inline u16 bf16_rne(float v) {
    unsigned u = __float_as_uint(v);
    return (u16)((u + 0x7fffu + ((u >> 16) & 1u)) >> 16);
}
__device__ inline float bf16_up(u16 h) { return __uint_as_float(((unsigned)h) << 16); }

__device__ inline void split2(float v, u16& hb, u16& lb) {
    hb = bf16_rne(v);
    lb = bf16_rne(v - bf16_up(hb));
}

__device__ inline int q8(float v, float scale) {
    int q = (int)rintf(v * scale);
    return q < -127 ? -127 : (q > 127 ? 127 : q);
}

__device__ inline void async_copy16(const void* g, void* l) {
    __builtin_amdgcn_global_load_lds(
        (const __attribute__((address_space(1))) void*)g,
        (__attribute__((address_space(3))) void*)l,
        16, 0, 0);
}

// ---------------- prep: codebook -> frag layout (bf16 hi + i8 lo + csq) ----------------
// cbf: [bc(128)][slot(13)][lane(64)][16B]
//  slot 0..7  : ch bf16, code=(bc*32+(lane&31)), d = slot*16 + (lane>>5)*8 + j
//  slot 8..11 : cl i8 (scale 2^13), d = (slot-8)*32 + (lane>>5)*16 + j (16 i8)
//  slot 12    : csq (lanes<32): k0=hi,k1=mid,k2=r2 (x -0.5), k3=320 (x 1.0)
__global__ __launch_bounds__(256)
void prep_kernel(const float* __restrict__ cb, u16* __restrict__ cbf,
                 float* __restrict__ csq, int* __restrict__ counter) {
    if (blockIdx.x >= 416) {                        // csq table + counter
        int idx = (blockIdx.x - 416) * 256 + threadIdx.x;   // 0..4095
        if (idx == 0) *counter = 0;
        const float4* p = (const float4*)(cb + (size_t)idx * DIM);
        float s = 0.f;
#pragma unroll
        for (int i = 0; i < DIM / 4; ++i) {
            float4 v = p[i];
            s += v.x * v.x + v.y * v.y + v.z * v.z + v.w * v.w;
        }
        csq[idx] = s;
        return;
    }
    int t    = blockIdx.x * 256 + threadIdx.x;      // 0..106495
    int lane = t & 63;
    int slotIdx = t >> 6;                           // 0..1663
    int slot = slotIdx % SLOTS;
    int bc   = slotIdx / SLOTS;                     // 0..127 = b*32+chunk

    u16 o[8] = {0, 0, 0, 0, 0, 0, 0, 0};
    if (slot < 8) {                                 // ch bf16
        int code = bc * CHUNK + (lane & 31);
        int d0   = slot * 16 + (lane >> 5) * 8;
        const float* row = cb + (size_t)code * DIM + d0;
        float4 v0 = *(const float4*)row;
        float4 v1 = *(const float4*)(row + 4);
        float vals[8] = {v0.x, v0.y, v0.z, v0.w, v1.x, v1.y, v1.z, v1.w};
#pragma unroll
        for (int j = 0; j < 8; ++j) o[j] = bf16_rne(vals[j]);
    } else if (slot < 12) {                         // cl i8, scale 8192
        int code = bc * CHUNK + (lane & 31);
        int d0   = (slot - 8) * 32 + (lane >> 5) * 16;
        const float* row = cb + (size_t)code * DIM + d0;
        unsigned* ow = (unsigned*)o;
#pragma unroll
        for (int wd = 0; wd < 4; ++wd) {
            unsigned pk = 0;
#pragma unroll
            for (int j = 0; j < 4; ++j) {
                float c = row[wd * 4 + j];
                float lo = c - bf16_up(bf16_rne(c));
                pk |= ((unsigned)(q8(lo, 8192.f) & 255)) << (8 * j);
            }
            ow[wd] = pk;
        }
    } else if (lane < 32) {                         // csq slice
        int code = bc * CHUNK + lane;
        const float4* p = (const float4*)(cb + (size_t)code * DIM);
        float ssum = 0.f;
#pragma unroll
        for (int i = 0; i < DIM / 4; ++i) {
            float4 v = p[i];
            ssum += v.x * v.x + v.y * v.y + v.z * v.z + v.w * v.w;
        }
        u16 hb = bf16_rne(ssum);
        float rem1 = ssum - bf16_up(hb);
        u16 mb = bf16_rne(rem1);
        u16 rb = bf16_rne(rem1 - bf16_up(mb));
        o[0] = hb; o[1] = mb; o[2] = rb;
        o[3] = (u16)0x43A0;                         // 320.0 bias
    }
    u16* dst = cbf + (size_t)t * 8;
#pragma unroll
    for (int j = 0; j < 8; ++j) dst[j] = o[j];
}

// ---------------- main: bf16 hh/hl + i8 cl*xh, 4 waves/SIMD, 1 barrier/chunk ----------
__global__ __launch_bounds__(256, 4)
void argmin_mfma_kernel(const float* __restrict__ x,
                        const u16*  __restrict__ cbf,
                        int* __restrict__ out,
                        int* __restrict__ counter,
                        int* __restrict__ worklist) {
    __shared__ u16 lds[2 * CHUNK_U16];              // 26624 B

    const int tid  = threadIdx.x;
    const int lane = tid & 63;
    const int w    = tid >> 6;
    const int n0   = blockIdx.x * BPTS;
    const int col  = lane & 31;
    const int kh   = lane >> 5;

    const char* src0 = (const char*)cbf;
    char* ldsb = (char*)lds;

    auto issue = [&](int c) {                       // stage chunk c -> buf[c&1]
        const char* src = src0 + (size_t)c * CHUNK_BYTES;
        char* dst = ldsb + (c & 1) * CHUNK_BYTES;
#pragma unroll
        for (int i = 0; i < 3; ++i)
            async_copy16(src + i * 4096 + tid * 16, dst + i * 4096 + w * 1024);
        if (tid < 64)
            async_copy16(src + 12288 + tid * 16, dst + 12288);
    };

    issue(0);

    // ---- x fragments for this wave's 32 points (overlaps chunk-0 staging) ----
    const float* xrow = x + (size_t)(n0 + w * 32 + col) * DIM;
    bf16x8 xh[8], xl[8];
#pragma unroll
    for (int s = 0; s < 8; ++s) {
        const float* p = xrow + s * 16 + kh * 8;
        float4 v0 = *(const float4*)p;
        float4 v1 = *(const float4*)(p + 4);
        float vals[8] = {v0.x, v0.y, v0.z, v0.w, v1.x, v1.y, v1.z, v1.w};
        bf16x8 hv, lv;
#pragma unroll
        for (int j = 0; j < 8; ++j) {
            u16 hb, lb;
            split2(vals[j], hb, lb);
            hv[j] = (short)hb;
            lv[j] = (short)lb;
        }
        xh[s] = hv;
        xl[s] = lv;
    }
    i32x4 xi8[4];                                   // xh quantized i8, scale 2^4
#pragma unroll
    for (int t = 0; t < 4; ++t) {
        const float* p = xrow + t * 32 + kh * 16;
        i32x4 fr;
#pragma unroll
        for (int wd = 0; wd < 4; ++wd) {
            unsigned pk = 0;
#pragma unroll
            for (int j = 0; j < 4; ++j) {
                float hx = bf16_up(bf16_rne(p[wd * 4 + j]));
                pk |= ((unsigned)(q8(hx, 16.f) & 255)) << (8 * j);
            }
            fr[wd] = (int)pk;
        }
        xi8[t] = fr;
    }
    bf16x8 xcf;                                     // csq B-frag
#pragma unroll
    for (int j = 0; j < 8; ++j) {
        short v = 0;
        if (kh == 0) {
            if (j < 3) v = (short)0xBF00;           // -0.5
            else if (j == 3) v = (short)0x3F80;     // 1.0
        }
        xcf[j] = v;
    }

    unsigned b1p = 0u, b2p = 0u;
    int bchunk = 0;

    __syncthreads();                                // chunk 0 visible

    for (int c = 0; c < NCH_ALL; ++c) {
        if (c + 1 < NCH_ALL) issue(c + 1);          // prefetch next chunk -> other buf

        const u16* A = &lds[(c & 1) * CHUNK_U16];
        f32x16 af;
        i32x16 ai;
#pragma unroll
        for (int r = 0; r < 16; ++r) { af[r] = 0.f; ai[r] = 0; }

#pragma unroll
        for (int s = 0; s < 8; ++s) {
            bf16x8 ahh = *(const bf16x8*)&A[s * 512 + lane * 8];
            af = __builtin_amdgcn_mfma_f32_32x32x16_bf16(ahh, xh[s], af, 0, 0, 0);
            af = __builtin_amdgcn_mfma_f32_32x32x16_bf16(ahh, xl[s], af, 0, 0, 0);
        }
#pragma unroll
        for (int t = 0; t < 4; ++t) {
            i32x4 ac8 = *(const i32x4*)&A[(8 + t) * 512 + lane * 8];
            ai = __builtin_amdgcn_mfma_i32_32x32x32_i8(ac8, xi8[t], ai, 0, 0, 0);
        }
        {   // csq + bias: af = ch.xh + ch.xl - csq/2 + 320
            bf16x8 acs = *(const bf16x8*)&A[12 * 512 + lane * 8];
            af = __builtin_amdgcn_mfma_f32_32x32x16_bf16(acs, xcf, af, 0, 0, 0);
        }

        // ---- packed top-2 argmax: total = af + ai*2^-17 (positive -> bits monotone) ----
        {
            unsigned prev = b1p, p1 = prev, p2 = b2p;
#pragma unroll
            for (int r = 0; r < 16; r += 2) {
                float va = fmaf((float)ai[r],     C17, af[r]);
                float vb = fmaf((float)ai[r + 1], C17, af[r + 1]);
                unsigned pa = (__float_as_uint(va) & 0xFFFFFFF0u) | (unsigned)(15 - r);
                unsigned pb = (__float_as_uint(vb) & 0xFFFFFFF0u) | (unsigned)(14 - r);
                unsigned hi = pa > pb ? pa : pb;
                unsigned lo = pa < pb ? pa : pb;
                unsigned t2 = hi < p1 ? hi : p1;
                unsigned m  = lo > t2 ? lo : t2;
                p2 = p2 > m ? p2 : m;               // -> v_max3
                p1 = p1 > hi ? p1 : hi;
            }
            bchunk = (p1 != prev) ? (c & 31) : bchunk;
            b1p = p1; b2p = p2;
        }

        if ((c & 31) == 31) {                       // ---- finalize book ----
            int b = c >> 5;
            unsigned leaf = b1p & 15u;
            int r = 15 - (int)leaf;
            float m1 = __uint_as_float(b1p & 0xFFFFFFF0u);
            float m2 = __uint_as_float(b2p & 0xFFFFFFF0u);
            int row = (r & 3) + 8 * (r >> 2) + 4 * kh;
            int code = bchunk * CHUNK + row;

            float om1 = __shfl_xor(m1, 32);
            float om2 = __shfl_xor(m2, 32);
            int   oc  = __shfl_xor(code, 32);
            bool take = (om1 > m1) || (om1 == m1 && oc < code);
            float nm2 = fmaxf(fminf(m1, om1), fmaxf(m2, om2));
            if (take) { m1 = om1; code = oc; }
            m2 = nm2;

            if (lane < 32) {
                int point = n0 + w * 32 + col;
                out[point * NBOOK + b] = code;
                if (m1 - m2 < EPS_ACC) {
                    int pos = atomicAdd(counter, 1);
                    if (pos < WL_CAP) worklist[pos] = point * NBOOK + b;
                }
            }
            b1p = 0u; b2p = 0u; bchunk = 0;
        }

        __syncthreads();                            // next-chunk loads done; buf reads done
    }
}

// ---------------- fallback: exact fp32 recompute for small-margin items ----------------
__global__ __launch_bounds__(256)
void exact_kernel(const float* __restrict__ x,
                  const float* __restrict__ cb,
                  const float* __restrict__ csq,
                  const int* __restrict__ counter,
                  const int* __restrict__ worklist,
                  int* __restrict__ out) {
    __shared__ float xs[DIM];
    __shared__ float rbest[4];
    __shared__ int   ribest[4];

    int nitems = *counter;
    if (nitems > WL_CAP) nitems = WL_CAP;

    for (int item = blockIdx.x; item < nitems; item += gridDim.x) {
        int nb = worklist[item];
        int n = nb >> 2, b = nb & 3;
        __syncthreads();
        if (threadIdx.x < 32) {
            float4 v = ((const float4*)(x + (size_t)n * DIM))[threadIdx.x];
            *(float4*)&xs[threadIdx.x * 4] = v;
        }
        __syncthreads();

        const float* cbb = cb + (size_t)b * KCODES * DIM;
        const float* crow[4];
#pragma unroll
        for (int kk = 0; kk < 4; ++kk)
            crow[kk] = cbb + (size_t)(kk * 256 + threadIdx.x) * DIM;

        float dots[4] = {0.f, 0.f, 0.f, 0.f};
#pragma unroll 8
        for (int d = 0; d < DIM; d += 4) {
            float4 xv = *(const float4*)&xs[d];
#pragma unroll
            for (int kk = 0; kk < 4; ++kk) {
                float4 cv = *(const float4*)(crow[kk] + d);
                dots[kk] += xv.x * cv.x + xv.y * cv.y + xv.z * cv.z + xv.w * cv.w;
            }
        }

        float bd = 3.4e38f;
        int   bi = 0;
#pragma unroll
        for (int kk = 0; kk < 4; ++kk) {
            int k = kk * 256 + threadIdx.x;
            float dist = csq[b * KCODES + k] - 2.f * dots[kk];
            if (dist < bd) { bd = dist; bi = k; }
        }
        for (int off = 1; off < 64; off <<= 1) {
            float od = __shfl_xor(bd, off);
            int   oi = __shfl_xor(bi, off);
            if (od < bd || (od == bd && oi < bi)) { bd = od; bi = oi; }
        }
        int w = threadIdx.x >> 6;
        if ((threadIdx.x & 63) == 0) { rbest[w] = bd; ribest[w] = bi; }
        __syncthreads();
        if (threadIdx.x == 0) {
            float fb = rbest[0]; int fi = ribest[0];
            for (int i = 1; i < 4; ++i) {
                if (rbest[i] < fb || (rbest[i] == fb && ribest[i] < fi)) {
                    fb = rbest[i]; fi = ribest[i];
                }
            }
            out[nb] = fi;
        }
    }
}

extern "C" void kernel_launch(void* const* d_in, const int* in_sizes, int n_in,
                              void* d_out, int out_size, void* d_ws, size_t ws_size,
                              hipStream_t stream) {
    const float* x  = (const float*)d_in[0];   // [N, D] fp32
    const float* cb = (const float*)d_in[1];   // [B, K, D] fp32
    int* out = (int*)d_out;                    // [N, B] int32

    char* ws = (char*)d_ws;
    u16*   cbf      = (u16*)ws;
    float* csq      = (float*)(ws + WS_CSQ_OFF);
    int*   counter  = (int*)(ws + WS_CNT_OFF);
    int*   worklist = (int*)(ws + WS_WL_OFF);

    prep_kernel<<<432, 256, 0, stream>>>(cb, cbf, csq, counter);

    argmin_mfma_kernel<<<N_PTS / BPTS, 256, 0, stream>>>(x, cbf, out, counter, worklist);

    exact_kernel<<<1024, 256, 0, stream>>>(x, cb, csq, counter, worklist, out);
}

// Round 8
// 460.333 us; speedup vs baseline: 1.1274x; 1.1274x over previous
//
#include <hip/hip_runtime.h>
#include <math.h>

#define N_PTS  131072
#define DIM    128
#define NBOOK  4
#define KCODES 1024

#define CHUNK   32                   // codes per chunk
#define NCH_ALL 128                  // 4 books x 32 chunks
#define BPTS    128                  // 4 waves x 32 points
#define SLOTS   13                   // 8 ch-bf16 + 4 cl-i8 + 1 csq
#define CHUNK_BYTES (SLOTS * 1024)   // 13312
#define CHUNK_U16   (SLOTS * 512)    // 6656
#define EPS_ACC   4.0e-3f            // flag margin (score units = dist/2)
#define ERR_GUARD 2.5e-3f            // bound on |approx-exact| incl. packing trunc
#define WL_CAP  131072
#define C17     7.62939453125e-6f    // 2^-17 = 1/(16*8192)

typedef short  bf16x8 __attribute__((ext_vector_type(8)));
typedef float  f32x16 __attribute__((ext_vector_type(16)));
typedef int    i32x4  __attribute__((ext_vector_type(4)));
typedef int    i32x16 __attribute__((ext_vector_type(16)));
typedef unsigned short u16;

// ws: cbf (128*13312 = 1703936 B) | csq fp32[4096] | counter | worklist (int4 x 131072)
#define WS_CSQ_OFF  1703936u
#define WS_CNT_OFF  (WS_CSQ_OFF + 16384u)
#define WS_WL_OFF   (WS_CNT_OFF + 256u)

__device__ inline u16 bf16_rne(float v) {
    unsigned u = __float_as_uint(v);
    return (u16)((u + 0x7fffu + ((u >> 16) & 1u)) >> 16);
}
__device__ inline float bf16_up(u16 h) { return __uint_as_float(((unsigned)h) << 16); }

__device__ inline void split2(float v, u16& hb, u16& lb) {
    hb = bf16_rne(v);
    lb = bf16_rne(v - bf16_up(hb));
}

__device__ inline int q8(float v, float scale) {
    int q = (int)rintf(v * scale);
    return q < -127 ? -127 : (q > 127 ? 127 : q);
}

__device__ inline void async_copy16(const void* g, void* l) {
    __builtin_amdgcn_global_load_lds(
        (const __attribute__((address_space(1))) void*)g,
        (__attribute__((address_space(3))) void*)l,
        16, 0, 0);
}

// ---------------- prep: codebook -> frag layout (bf16 hi + i8 lo + csq) ----------------
// cbf: [bc(128)][slot(13)][lane(64)][16B]
//  slot 0..7  : ch bf16, code=(bc*32+(lane&31)), d = slot*16 + (lane>>5)*8 + j
//  slot 8..11 : cl i8 (scale 2^13), d = (slot-8)*32 + (lane>>5)*16 + j (16 i8)
//  slot 12    : csq (lanes<32): k0=hi,k1=mid,k2=r2 (x -0.5), k3=320 (x 1.0 bias)
__global__ __launch_bounds__(256)
void prep_kernel(const float* __restrict__ cb, u16* __restrict__ cbf,
                 float* __restrict__ csq, int* __restrict__ counter) {
    if (blockIdx.x >= 416) {                        // csq table + counter
        int idx = (blockIdx.x - 416) * 256 + threadIdx.x;   // 0..4095
        if (idx == 0) *counter = 0;
        const float4* p = (const float4*)(cb + (size_t)idx * DIM);
        float s = 0.f;
#pragma unroll
        for (int i = 0; i < DIM / 4; ++i) {
            float4 v = p[i];
            s += v.x * v.x + v.y * v.y + v.z * v.z + v.w * v.w;
        }
        csq[idx] = s;
        return;
    }
    int t    = blockIdx.x * 256 + threadIdx.x;      // 0..106495
    int lane = t & 63;
    int slotIdx = t >> 6;                           // 0..1663
    int slot = slotIdx % SLOTS;
    int bc   = slotIdx / SLOTS;                     // 0..127 = b*32+chunk

    u16 o[8] = {0, 0, 0, 0, 0, 0, 0, 0};
    if (slot < 8) {                                 // ch bf16
        int code = bc * CHUNK + (lane & 31);
        int d0   = slot * 16 + (lane >> 5) * 8;
        const float* row = cb + (size_t)code * DIM + d0;
        float4 v0 = *(const float4*)row;
        float4 v1 = *(const float4*)(row + 4);
        float vals[8] = {v0.x, v0.y, v0.z, v0.w, v1.x, v1.y, v1.z, v1.w};
#pragma unroll
        for (int j = 0; j < 8; ++j) o[j] = bf16_rne(vals[j]);
    } else if (slot < 12) {                         // cl i8, scale 8192
        int code = bc * CHUNK + (lane & 31);
        int d0   = (slot - 8) * 32 + (lane >> 5) * 16;
        const float* row = cb + (size_t)code * DIM + d0;
        unsigned* ow = (unsigned*)o;
#pragma unroll
        for (int wd = 0; wd < 4; ++wd) {
            unsigned pk = 0;
#pragma unroll
            for (int j = 0; j < 4; ++j) {
                float c = row[wd * 4 + j];
                float lo = c - bf16_up(bf16_rne(c));
                pk |= ((unsigned)(q8(lo, 8192.f) & 255)) << (8 * j);
            }
            ow[wd] = pk;
        }
    } else if (lane < 32) {                         // csq slice
        int code = bc * CHUNK + lane;
        const float4* p = (const float4*)(cb + (size_t)code * DIM);
        float ssum = 0.f;
#pragma unroll
        for (int i = 0; i < DIM / 4; ++i) {
            float4 v = p[i];
            ssum += v.x * v.x + v.y * v.y + v.z * v.z + v.w * v.w;
        }
        u16 hb = bf16_rne(ssum);
        float rem1 = ssum - bf16_up(hb);
        u16 mb = bf16_rne(rem1);
        u16 rb = bf16_rne(rem1 - bf16_up(mb));
        o[0] = hb; o[1] = mb; o[2] = rb;
        o[3] = (u16)0x43A0;                         // 320.0 bias
    }
    u16* dst = cbf + (size_t)t * 8;
#pragma unroll
    for (int j = 0; j < 8; ++j) dst[j] = o[j];
}

// ---------------- main: bf16 hh/hl + i8 cl*xh, top-2 with code ids --------------------
__global__ __launch_bounds__(256, 3)
void argmin_mfma_kernel(const float* __restrict__ x,
                        const u16*  __restrict__ cbf,
                        int* __restrict__ out,
                        int* __restrict__ counter,
                        int4* __restrict__ worklist) {
    __shared__ u16 lds[2 * CHUNK_U16];              // 26624 B

    const int tid  = threadIdx.x;
    const int lane = tid & 63;
    const int w    = tid >> 6;
    const int n0   = blockIdx.x * BPTS;
    const int col  = lane & 31;
    const int kh   = lane >> 5;

    const char* src0 = (const char*)cbf;
    char* ldsb = (char*)lds;

    auto issue = [&](int c) {                       // stage chunk c -> buf[c&1]
        const char* src = src0 + (size_t)c * CHUNK_BYTES;
        char* dst = ldsb + (c & 1) * CHUNK_BYTES;
#pragma unroll
        for (int i = 0; i < 3; ++i)
            async_copy16(src + i * 4096 + tid * 16, dst + i * 4096 + w * 1024);
        if (tid < 64)
            async_copy16(src + 12288 + tid * 16, dst + 12288);
    };

    issue(0);

    // ---- x fragments for this wave's 32 points (overlaps chunk-0 staging) ----
    const float* xrow = x + (size_t)(n0 + w * 32 + col) * DIM;
    bf16x8 xh[8], xl[8];
#pragma unroll
    for (int s = 0; s < 8; ++s) {
        const float* p = xrow + s * 16 + kh * 8;
        float4 v0 = *(const float4*)p;
        float4 v1 = *(const float4*)(p + 4);
        float vals[8] = {v0.x, v0.y, v0.z, v0.w, v1.x, v1.y, v1.z, v1.w};
        bf16x8 hv, lv;
#pragma unroll
        for (int j = 0; j < 8; ++j) {
            u16 hb, lb;
            split2(vals[j], hb, lb);
            hv[j] = (short)hb;
            lv[j] = (short)lb;
        }
        xh[s] = hv;
        xl[s] = lv;
    }
    i32x4 xi8[4];                                   // xh quantized i8, scale 2^4
#pragma unroll
    for (int t = 0; t < 4; ++t) {
        const float* p = xrow + t * 32 + kh * 16;
        i32x4 fr;
#pragma unroll
        for (int wd = 0; wd < 4; ++wd) {
            unsigned pk = 0;
#pragma unroll
            for (int j = 0; j < 4; ++j) {
                float hx = bf16_up(bf16_rne(p[wd * 4 + j]));
                pk |= ((unsigned)(q8(hx, 16.f) & 255)) << (8 * j);
            }
            fr[wd] = (int)pk;
        }
        xi8[t] = fr;
    }
    bf16x8 xcf;                                     // csq B-frag
#pragma unroll
    for (int j = 0; j < 8; ++j) {
        short v = 0;
        if (kh == 0) {
            if (j < 3) v = (short)0xBF00;           // -0.5
            else if (j == 3) v = (short)0x3F80;     // 1.0
        }
        xcf[j] = v;
    }

    unsigned g1 = 0u, g2 = 0u, k1 = 0u, k2 = 0u;    // top-2 packed + chunk ids

    __syncthreads();                                // chunk 0 visible

    for (int c = 0; c < NCH_ALL; ++c) {
        if (c + 1 < NCH_ALL) issue(c + 1);          // prefetch next chunk -> other buf

        const u16* A = &lds[(c & 1) * CHUNK_U16];
        f32x16 af;
        i32x16 ai;
#pragma unroll
        for (int r = 0; r < 16; ++r) { af[r] = 0.f; ai[r] = 0; }

#pragma unroll
        for (int s = 0; s < 8; ++s) {
            bf16x8 ahh = *(const bf16x8*)&A[s * 512 + lane * 8];
            af = __builtin_amdgcn_mfma_f32_32x32x16_bf16(ahh, xh[s], af, 0, 0, 0);
            af = __builtin_amdgcn_mfma_f32_32x32x16_bf16(ahh, xl[s], af, 0, 0, 0);
        }
#pragma unroll
        for (int t = 0; t < 4; ++t) {
            i32x4 ac8 = *(const i32x4*)&A[(8 + t) * 512 + lane * 8];
            ai = __builtin_amdgcn_mfma_i32_32x32x32_i8(ac8, xi8[t], ai, 0, 0, 0);
        }
        {   // csq + bias: af = ch.xh + ch.xl - csq/2 + 320
            bf16x8 acs = *(const bf16x8*)&A[12 * 512 + lane * 8];
            af = __builtin_amdgcn_mfma_f32_32x32x16_bf16(acs, xcf, af, 0, 0, 0);
        }

        // ---- chunk-local top-2 (packed: [score-bits|15-leaf], larger = nearer) ----
        {
            unsigned t1[4], t2[4];
#pragma unroll
            for (int g = 0; g < 2; ++g) {           // two groups of 8 regs
                unsigned p1[4], p2[4];
#pragma unroll
                for (int i = 0; i < 4; ++i) {
                    int r = g * 8 + 2 * i;
                    float va = fmaf((float)ai[r],     C17, af[r]);
                    float vb = fmaf((float)ai[r + 1], C17, af[r + 1]);
                    unsigned pa = (__float_as_uint(va) & 0xFFFFFFF0u) | (unsigned)(15 - r);
                    unsigned pb = (__float_as_uint(vb) & 0xFFFFFFF0u) | (unsigned)(14 - r);
                    p1[i] = pa > pb ? pa : pb;
                    p2[i] = pa < pb ? pa : pb;
                }
                // top2(a) ∪ top2(b): h1=max(a1,b1), h2=max(min(a1,b1),a2,b2)
                unsigned q1 = p1[0] > p1[1] ? p1[0] : p1[1];
                unsigned qm = p1[0] < p1[1] ? p1[0] : p1[1];
                unsigned q2 = p2[0] > p2[1] ? p2[0] : p2[1];
                q2 = qm > q2 ? qm : q2;
                unsigned r1 = p1[2] > p1[3] ? p1[2] : p1[3];
                unsigned rm = p1[2] < p1[3] ? p1[2] : p1[3];
                unsigned r2 = p2[2] > p2[3] ? p2[2] : p2[3];
                r2 = rm > r2 ? rm : r2;
                t1[g] = q1 > r1 ? q1 : r1;
                unsigned tm = q1 < r1 ? q1 : r1;
                unsigned tt = q2 > r2 ? q2 : r2;
                t2[g] = tm > tt ? tm : tt;
            }
            unsigned h1 = t1[0] > t1[1] ? t1[0] : t1[1];
            unsigned hm = t1[0] < t1[1] ? t1[0] : t1[1];
            unsigned ht = t2[0] > t2[1] ? t2[0] : t2[1];
            unsigned h2 = hm > ht ? hm : ht;

            // ---- merge into global top-2 with chunk ids (strict >: first-min ties) ----
            unsigned ci = (unsigned)(c & 31);
            bool rep = h1 > g1;
            unsigned s_val = rep ? (h2 > g1 ? h2 : g1) : (h1 > g2 ? h1 : g2);
            unsigned s_k   = rep ? (h2 > g1 ? ci : k1) : (h1 > g2 ? ci : k2);
            if (rep) { g1 = h1; k1 = ci; }
            g2 = s_val; k2 = s_k;
        }

        if ((c & 31) == 31) {                       // ---- finalize book ----
            int b = c >> 5;
            int r1i = 15 - (int)(g1 & 15u);
            int r2i = 15 - (int)(g2 & 15u);
            int code1 = (int)k1 * CHUNK + (r1i & 3) + 8 * (r1i >> 2) + 4 * kh;
            int code2 = (int)k2 * CHUNK + (r2i & 3) + 8 * (r2i >> 2) + 4 * kh;
            unsigned v1 = g1 & 0xFFFFFFF0u;
            unsigned v2 = g2 & 0xFFFFFFF0u;

            unsigned ov1 = (unsigned)__shfl_xor((int)v1, 32);
            unsigned ov2 = (unsigned)__shfl_xor((int)v2, 32);
            int oc1 = __shfl_xor(code1, 32);
            int oc2 = __shfl_xor(code2, 32);

            bool take = (ov1 > v1) || (ov1 == v1 && oc1 < code1);
            unsigned w1 = take ? ov1 : v1;  int wc1 = take ? oc1 : code1;
            unsigned lh = take ? v1 : ov1;  int lhc = take ? code1 : oc1;
            unsigned ws = take ? ov2 : v2;  int wsc = take ? oc2 : code2;
            bool slh = (lh > ws) || (lh == ws && lhc < wsc);
            unsigned w2 = slh ? lh : ws;    int wc2 = slh ? lhc : wsc;

            if (lane < 32) {
                int nb = (n0 + w * 32 + col) * NBOOK + b;
                out[nb] = wc1;
                float m1f = __uint_as_float(w1);
                float m2f = __uint_as_float(w2);
                if (m1f - m2f < EPS_ACC) {
                    int pos = atomicAdd(counter, 1);
                    if (pos < WL_CAP)
                        worklist[pos] = make_int4(nb, wc1 | (wc2 << 16), (int)w2, 0);
                }
            }
            g1 = 0u; g2 = 0u; k1 = 0u; k2 = 0u;
        }

        __syncthreads();                            // next-chunk loads done; buf reads done
    }
}

// ---------------- pair fallback: exact fp32 on the two candidates --------------------
// one wave per item; guard failure -> in-wave full scan (rare, correct-by-construction)
__global__ __launch_bounds__(256)
void pair_kernel(const float* __restrict__ x,
                 const float* __restrict__ cb,
                 const float* __restrict__ csq,
                 const int* __restrict__ counter,
                 const int4* __restrict__ worklist,
                 int* __restrict__ out) {
    __shared__ float xs[4][DIM];

    const int lane = threadIdx.x & 63;
    const int w    = threadIdx.x >> 6;

    int nitems = *counter;
    if (nitems > WL_CAP) nitems = WL_CAP;

    for (int it = blockIdx.x * 4 + w; it < nitems; it += gridDim.x * 4) {
        int4 e = worklist[it];
        int nb = e.x;
        int n = nb >> 2, b = nb & 3;
        int c1 = e.y & 0xFFFF, c2 = (e.y >> 16) & 0xFFFF;
        float m2f = __uint_as_float((unsigned)e.z);

        const float* xr = x + (size_t)n * DIM;
        const float* cbb = cb + (size_t)b * KCODES * DIM;

        float2 xv = *(const float2*)(xr + lane * 2);
        xs[w][lane * 2]     = xv.x;
        xs[w][lane * 2 + 1] = xv.y;
        float2 a1 = *(const float2*)(cbb + (size_t)c1 * DIM + lane * 2);
        float2 a2 = *(const float2*)(cbb + (size_t)c2 * DIM + lane * 2);
        float d1 = xv.x * a1.x + xv.y * a1.y;
        float d2 = xv.x * a2.x + xv.y * a2.y;
#pragma unroll
        for (int off = 32; off > 0; off >>= 1) {
            d1 += __shfl_xor(d1, off);
            d2 += __shfl_xor(d2, off);
        }
        float e1 = d1 - 0.5f * csq[b * KCODES + c1] + 320.f;
        float e2 = d2 - 0.5f * csq[b * KCODES + c2] + 320.f;

        bool first = (e1 > e2) || (e1 == e2 && c1 < c2);
        int  bw = first ? c1 : c2;
        float ew = fmaxf(e1, e2);

        if (ew >= m2f + ERR_GUARD) {
            if (lane == 0) out[nb] = bw;
            continue;
        }

        // ---- rare: genuine multi-way near-tie -> exact full scan by this wave ----
        __threadfence_block();                      // xs[w] visible to whole wave
        float bd = 3.4e38f;
        int   bi = 0;
        for (int j = 0; j < KCODES / 64; ++j) {
            int k = j * 64 + lane;
            const float* row = cbb + (size_t)k * DIM;
            float dot = 0.f;
#pragma unroll 8
            for (int d = 0; d < DIM; d += 4) {
                float4 rv = *(const float4*)(row + d);
                dot += xs[w][d] * rv.x + xs[w][d + 1] * rv.y
                     + xs[w][d + 2] * rv.z + xs[w][d + 3] * rv.w;
            }
            float dist = csq[b * KCODES + k] - 2.f * dot;
            if (dist < bd) { bd = dist; bi = k; }
        }
#pragma unroll
        for (int off = 1; off < 64; off <<= 1) {
            float od = __shfl_xor(bd, off);
            int   oi = __shfl_xor(bi, off);
            if (od < bd || (od == bd && oi < bi)) { bd = od; bi = oi; }
        }
        if (lane == 0) out[nb] = bi;
    }
}

extern "C" void kernel_launch(void* const* d_in, const int* in_sizes, int n_in,
                              void* d_out, int out_size, void* d_ws, size_t ws_size,
                              hipStream_t stream) {
    const float* x  = (const float*)d_in[0];   // [N, D] fp32
    const float* cb = (const float*)d_in[1];   // [B, K, D] fp32
    int* out = (int*)d_out;                    // [N, B] int32

    char* ws = (char*)d_ws;
    u16*   cbf      = (u16*)ws;
    float* csq      = (float*)(ws + WS_CSQ_OFF);
    int*   counter  = (int*)(ws + WS_CNT_OFF);
    int4*  worklist = (int4*)(ws + WS_WL_OFF);

    prep_kernel<<<432, 256, 0, stream>>>(cb, cbf, csq, counter);

    argmin_mfma_kernel<<<N_PTS / BPTS, 256, 0, stream>>>(x, cbf, out, counter, worklist);

    pair_kernel<<<256, 256, 0, stream>>>(x, cb, csq, counter, worklist, out);
}